// Round 1
// 867.660 us; speedup vs baseline: 1.3334x; 1.3334x over previous
//
#include <hip/hip_runtime.h>
#include <hip/hip_bf16.h>

// Problem constants (from reference)
#define NN   100000   // nodes
#define NE   600000   // edges
#define INC  128      // in channels
#define HC   128      // heads*per_head = 2*64
#define NH   2        // heads
#define TDIM 64       // time enc dim
#define MSGD 64       // msg dim
#define EDD  128      // edge_attr dim = TDIM + MSGD

#define EPB  64       // edges per block (K2 tile M)
#define NPB  64       // nodes per block (K1 tile M)
#define LDK  (EDD + 8)  // padded row (bf16 elems) for A operand tiles
#define LDC  (HC + 8)   // padded row for C tiles

typedef __hip_bfloat16 bf16;
typedef __attribute__((ext_vector_type(8))) short short8;
typedef __attribute__((ext_vector_type(4))) float floatx4;

static __device__ __forceinline__ float b2f(bf16 h) { return __bfloat162float(h); }
static __device__ __forceinline__ bf16  f2b(float f) { return __float2bfloat16(f); }
static __device__ __forceinline__ float2 bload2(const bf16* p) {
    __hip_bfloat162 h = *reinterpret_cast<const __hip_bfloat162*>(p);
    return __bfloat1622float2(h);
}

// ---------------------------------------------------------------------------
// K0: zero the output accumulator and softmax denominators
// ---------------------------------------------------------------------------
__global__ __launch_bounds__(256) void k0_init(float* __restrict__ out_acc, float* __restrict__ denom)
{
    int tid = blockIdx.x * 256 + threadIdx.x;
    if (tid < NN * HC) out_acc[tid] = 0.0f;
    if (tid < NN * NH) denom[tid] = 0.0f;
}

// ---------------------------------------------------------------------------
// K0b: convert the 5 weight matrices to bf16 *MFMA B-fragment order*:
// wF[mat][k0g][nt][lane][j] = W[k][n]  with n = nt*16 + (lane&15),
//                                         k = k0g*32 + (lane>>4)*8 + j
// so each wave's B operand for (k0g,nt) is ONE coalesced 1KB load.
// ---------------------------------------------------------------------------
__global__ __launch_bounds__(256) void k0b_frag(
    const float* __restrict__ Wq, const float* __restrict__ Wk,
    const float* __restrict__ Wv, const float* __restrict__ Wsk,
    const float* __restrict__ We, bf16* __restrict__ wF)
{
    int tid = blockIdx.x * 256 + threadIdx.x;
    if (tid >= 5 * 16384) return;
    int mat  = tid >> 14;
    int pos  = tid & 16383;
    int j    = pos & 7;
    int lane = (pos >> 3) & 63;
    int nt   = (pos >> 9) & 7;
    int k0g  = pos >> 12;                 // 0..3
    int n = nt * 16 + (lane & 15);
    int k = k0g * 32 + (lane >> 4) * 8 + j;
    const float* W = (mat == 0) ? Wq : (mat == 1) ? Wk : (mat == 2) ? Wv : (mat == 3) ? Wsk : We;
    wF[tid] = f2b(W[k * 128 + n]);
}

// ---------------------------------------------------------------------------
// K1: node projections via MFMA. 64 nodes x 128 cols per block; g-loop over
// {Wq,Wk,Wv,Wskip}. B-fragments come straight from global wF (coalesced,
// L2-resident) -> no 34.8KB wts tile in LDS -> higher occupancy.
// q/k/v -> bf16 (LDS-assembled coalesced stores); skip -> f32 into d_out.
// ---------------------------------------------------------------------------
__global__ __launch_bounds__(256) void k1_node_proj(
    const float* __restrict__ x, const bf16* __restrict__ wF,
    const float* __restrict__ bq, const float* __restrict__ bk,
    const float* __restrict__ bv, const float* __restrict__ bsk,
    bf16* __restrict__ qn, bf16* __restrict__ kn, bf16* __restrict__ vn,
    float* __restrict__ skipv)
{
    __shared__ __align__(16) bf16 xs[NPB * LDK];    // 17.4 KB
    __shared__ __align__(16) bf16 outs[NPB * LDC];  // 17.4 KB
    __shared__ float bias_s[4 * HC];

    int tid = threadIdx.x;
    int lane = tid & 63, wave = tid >> 6;
    int n0node = blockIdx.x * NPB;

    // stage x tile as bf16 (A-operand layout [m][k], padded)
    for (int idx = tid; idx < NPB * (INC / 4); idx += 256) {
        int m = idx >> 5, c4 = idx & 31;
        int node = n0node + m;
        float4 v = (node < NN) ? reinterpret_cast<const float4*>(x)[(size_t)node * 32 + c4]
                               : make_float4(0.f, 0.f, 0.f, 0.f);
        union { bf16 h[4]; uint2 u; } pk;
        pk.h[0] = f2b(v.x); pk.h[1] = f2b(v.y); pk.h[2] = f2b(v.z); pk.h[3] = f2b(v.w);
        *reinterpret_cast<uint2*>(&xs[m * LDK + c4 * 4]) = pk.u;
    }
    for (int i = tid; i < 4 * HC; i += 256) {
        const float* B = (i < 128) ? bq : (i < 256) ? bk : (i < 384) ? bv : bsk;
        bias_s[i] = B[i & 127];
    }
    __syncthreads();

    bf16* Os[3] = {qn, kn, vn};
    int m0 = wave * 16, r = lane & 15, quad = lane >> 4;

    for (int g = 0; g < 4; ++g) {
        const short8* Bf = reinterpret_cast<const short8*>(wF + (size_t)g * 16384);

        floatx4 acc[8];
        #pragma unroll
        for (int i = 0; i < 8; ++i) acc[i] = (floatx4){0.f, 0.f, 0.f, 0.f};

        #pragma unroll
        for (int k0g = 0; k0g < 4; ++k0g) {
            short8 a = *reinterpret_cast<const short8*>(&xs[(m0 + r) * LDK + k0g * 32 + quad * 8]);
            #pragma unroll
            for (int nt = 0; nt < 8; ++nt) {
                short8 b = Bf[(k0g * 8 + nt) * 64 + lane];
                acc[nt] = __builtin_amdgcn_mfma_f32_16x16x32_bf16(a, b, acc[nt], 0, 0, 0);
            }
        }

        if (g < 3) {
            // C layout: col=lane&15, row=quad*4+reg -> assemble in LDS, coalesced store
            #pragma unroll
            for (int nt = 0; nt < 8; ++nt) {
                int col = nt * 16 + r;
                float bsv = bias_s[g * HC + col];
                #pragma unroll
                for (int rg = 0; rg < 4; ++rg) {
                    int row = m0 + quad * 4 + rg;
                    outs[row * LDC + col] = f2b(acc[nt][rg] + bsv);
                }
            }
            __syncthreads();
            bf16* dst = Os[g];
            for (int idx = tid; idx < NPB * (HC / 8); idx += 256) {
                int row = idx >> 4, seg = idx & 15;
                int node = n0node + row;
                if (node < NN)
                    *reinterpret_cast<uint4*>(dst + (size_t)node * HC + seg * 8) =
                        *reinterpret_cast<const uint4*>(&outs[row * LDC + seg * 8]);
            }
            __syncthreads();
        } else {
            // skip connection: f32 direct stores into d_out
            #pragma unroll
            for (int nt = 0; nt < 8; ++nt) {
                int col = nt * 16 + r;
                float bsv = bias_s[3 * HC + col];
                #pragma unroll
                for (int rg = 0; rg < 4; ++rg) {
                    int node = n0node + m0 + quad * 4 + rg;
                    if (node < NN) skipv[(size_t)node * HC + col] = acc[nt][rg] + bsv;
                }
            }
        }
    }
}

// ---------------------------------------------------------------------------
// K2 (fused): per 64-edge block:
//   e = [cos(rel*wt+bt), msg] @ We  (MFMA, B-fragments from global)
//   ex = exp(q[dst].(k[src]+e)/8)   (no-max softmax: exact math identity)
//   atomicAdd out_acc[dst] += ex*(v[src]+e);  atomicAdd denom[dst,h] += ex
// No e_ws / alpha / amax round-trips. LDS ~19KB -> much higher occupancy.
// e tile aliases the edge_attr tile (each wave touches only its own 16 rows).
// ---------------------------------------------------------------------------
__global__ __launch_bounds__(256) void k2_fused(
    const int* __restrict__ eidx,
    const float* __restrict__ lu, const float* __restrict__ t, const float* __restrict__ msg,
    const float* __restrict__ wtv, const float* __restrict__ btv,
    const bf16* __restrict__ wFe,
    const bf16* __restrict__ qn, const bf16* __restrict__ kn, const bf16* __restrict__ vn,
    float* __restrict__ out_acc, float* __restrict__ denom)
{
    __shared__ __align__(16) bf16 tile[EPB * LDK];  // edge_attr, then aliased e  (17.4 KB)
    __shared__ float wt_s[TDIM], bt_s[TDIM];
    __shared__ float rel_s[EPB];
    __shared__ int src_s[EPB], dst_s[EPB];

    int tid = threadIdx.x;
    int lane = tid & 63, wave = tid >> 6;
    int e0 = blockIdx.x * EPB;   // NE % EPB == 0, no guards needed

    if (tid < TDIM) { wt_s[tid] = wtv[tid]; bt_s[tid] = btv[tid]; }
    if (tid < EPB) {
        int s = eidx[e0 + tid];
        int d = eidx[NE + e0 + tid];
        src_s[tid] = s; dst_s[tid] = d;
        rel_s[tid] = lu[s] - t[e0 + tid];
    }
    __syncthreads();

    // build edge_attr tile (bf16, A-operand layout); msg half vectorized
    for (int idx = tid; idx < EPB * (EDD / 4); idx += 256) {
        int m = idx >> 5, c4 = idx & 31;
        union { bf16 h[4]; uint2 u; } pk;
        if (c4 < 16) {
            float rv = rel_s[m];
            #pragma unroll
            for (int j = 0; j < 4; ++j) {
                int d = c4 * 4 + j;
                pk.h[j] = f2b(cosf(fmaf(rv, wt_s[d], bt_s[d])));
            }
        } else {
            float4 v = reinterpret_cast<const float4*>(msg)[(size_t)(e0 + m) * (MSGD / 4) + (c4 - 16)];
            pk.h[0] = f2b(v.x); pk.h[1] = f2b(v.y); pk.h[2] = f2b(v.z); pk.h[3] = f2b(v.w);
        }
        *reinterpret_cast<uint2*>(&tile[m * LDK + c4 * 4]) = pk.u;
    }
    __syncthreads();

    int m0 = wave * 16, r = lane & 15, quad = lane >> 4;
    const short8* Bf = reinterpret_cast<const short8*>(wFe);

    floatx4 acc[8];
    #pragma unroll
    for (int i = 0; i < 8; ++i) acc[i] = (floatx4){0.f, 0.f, 0.f, 0.f};

    #pragma unroll
    for (int k0g = 0; k0g < 4; ++k0g) {
        short8 a = *reinterpret_cast<const short8*>(&tile[(m0 + r) * LDK + k0g * 32 + quad * 8]);
        #pragma unroll
        for (int nt = 0; nt < 8; ++nt) {
            short8 b = Bf[(k0g * 8 + nt) * 64 + lane];
            acc[nt] = __builtin_amdgcn_mfma_f32_16x16x32_bf16(a, b, acc[nt], 0, 0, 0);
        }
    }

    // e tile -> LDS, aliased over edge_attr rows. Wave w reads (A-frags) and
    // writes (e) ONLY rows [m0, m0+16) -> within-wave ordering suffices.
    #pragma unroll
    for (int nt = 0; nt < 8; ++nt) {
        int col = nt * 16 + r;
        #pragma unroll
        for (int rg = 0; rg < 4; ++rg) {
            tile[(m0 + quad * 4 + rg) * LDK + col] = f2b(acc[nt][rg]);
        }
    }

    // fused epilogue: each wave its own 16 edges; lanes cover 128 channels (2 each)
    int half = lane >> 5;   // head
    #pragma unroll 4
    for (int i = 0; i < 16; ++i) {
        int m = m0 + i;
        int srcn = src_s[m], dstn = dst_s[m];
        float2 qv = bload2(&qn[(size_t)dstn * HC + 2 * lane]);
        float2 kv = bload2(&kn[(size_t)srcn * HC + 2 * lane]);
        float2 ev = bload2(&tile[m * LDK + 2 * lane]);
        float part = qv.x * (kv.x + ev.x) + qv.y * (kv.y + ev.y);
        part += __shfl_xor(part, 1);
        part += __shfl_xor(part, 2);
        part += __shfl_xor(part, 4);
        part += __shfl_xor(part, 8);
        part += __shfl_xor(part, 16);      // all 32 lanes of each head hold the dot
        float ex = __expf(part * 0.125f);  // 1/sqrt(64); no max-subtraction needed
        float2 vv = bload2(&vn[(size_t)srcn * HC + 2 * lane]);
        atomicAdd(&out_acc[(size_t)dstn * HC + 2 * lane],     ex * (vv.x + ev.x));
        atomicAdd(&out_acc[(size_t)dstn * HC + 2 * lane + 1], ex * (vv.y + ev.y));
        if ((lane & 31) == 0) atomicAdd(&denom[dstn * NH + half], ex);
    }
}

// ---------------------------------------------------------------------------
// K5: out = skip (already in d_out) + out_acc / denom
// ---------------------------------------------------------------------------
__global__ __launch_bounds__(256) void k5_final(
    const float* __restrict__ out_acc, const float* __restrict__ denom,
    float* __restrict__ out)
{
    int tid = blockIdx.x * 256 + threadIdx.x;
    if (tid >= NN * HC) return;
    int node = tid >> 7, h = (tid >> 6) & 1;
    out[tid] = out[tid] + out_acc[tid] / (denom[node * NH + h] + 1e-16f);
}

// ---------------------------------------------------------------------------
extern "C" void kernel_launch(void* const* d_in, const int* in_sizes, int n_in,
                              void* d_out, int out_size, void* d_ws, size_t ws_size,
                              hipStream_t stream)
{
    const float* x   = (const float*)d_in[0];
    const float* lu  = (const float*)d_in[1];
    const int*   eidx= (const int*)d_in[2];
    const float* t   = (const float*)d_in[3];
    const float* msg = (const float*)d_in[4];
    const float* wt  = (const float*)d_in[5];
    const float* bt  = (const float*)d_in[6];
    const float* Wq  = (const float*)d_in[7];
    const float* bq  = (const float*)d_in[8];
    const float* Wk  = (const float*)d_in[9];
    const float* bk  = (const float*)d_in[10];
    const float* Wv  = (const float*)d_in[11];
    const float* bv  = (const float*)d_in[12];
    const float* We  = (const float*)d_in[13];
    const float* Wsk = (const float*)d_in[14];
    const float* bsk = (const float*)d_in[15];
    float* out = (float*)d_out;

    // workspace layout (all offsets 16B-aligned)
    char* ws = (char*)d_ws;
    size_t off = 0;
    bf16*  qn      = (bf16*)(ws + off);  off += (size_t)NN * HC * 2;       // 25.6 MB
    bf16*  kn      = (bf16*)(ws + off);  off += (size_t)NN * HC * 2;       // 25.6 MB
    bf16*  vn      = (bf16*)(ws + off);  off += (size_t)NN * HC * 2;       // 25.6 MB
    float* out_acc = (float*)(ws + off); off += (size_t)NN * HC * 4;       // 51.2 MB
    float* denom   = (float*)(ws + off); off += (size_t)NN * NH * 4;       // 0.8 MB
    bf16*  wF      = (bf16*)(ws + off);  off += (size_t)5 * 128 * 128 * 2; // 0.16 MB

    k0_init<<<(NN * HC + 255) / 256, 256, 0, stream>>>(out_acc, denom);

    k0b_frag<<<(5 * 16384) / 256, 256, 0, stream>>>(Wq, Wk, Wv, Wsk, We, wF);

    k1_node_proj<<<(NN + NPB - 1) / NPB, 256, 0, stream>>>(
        x, wF, bq, bk, bv, bsk, qn, kn, vn, out);

    k2_fused<<<NE / EPB, 256, 0, stream>>>(
        eidx, lu, t, msg, wt, bt, wF + (size_t)4 * 16384,
        qn, kn, vn, out_acc, denom);

    k5_final<<<(NN * HC + 255) / 256, 256, 0, stream>>>(out_acc, denom, out);
}